// Round 4
// baseline (746.340 us; speedup 1.0000x reference)
//
#include <hip/hip_runtime.h>

#define N_NODES 100000
#define D_FEAT 64
#define RPB 256                               // rows per bucket
#define NB ((N_NODES + RPB - 1) / RPB)        // 391 buckets
#define CHUNK 4096                            // edges per partition block
#define SCAN_T 512

// ---------- K1: bucket-size histogram ----------
__global__ void count_kernel(const int* __restrict__ row, int* __restrict__ bucketCnt, int E) {
    __shared__ int h[NB];
    for (int i = threadIdx.x; i < NB; i += blockDim.x) h[i] = 0;
    __syncthreads();
    int base = blockIdx.x * CHUNK;
    int end = min(base + CHUNK, E);
    for (int e = base + threadIdx.x; e < end; e += blockDim.x)
        atomicAdd(&h[row[e] >> 8], 1);
    __syncthreads();
    for (int i = threadIdx.x; i < NB; i += blockDim.x)
        if (h[i]) atomicAdd(&bucketCnt[i], h[i]);
}

// ---------- K2: scan bucket sizes -> base & cursor ----------
__global__ void bscan_kernel(const int* __restrict__ bucketCnt, int* __restrict__ bucketBase,
                             int* __restrict__ bucketCursor) {
    __shared__ int s[SCAN_T];
    int t = threadIdx.x;
    s[t] = (t < NB) ? bucketCnt[t] : 0;
    __syncthreads();
    for (int off = 1; off < SCAN_T; off <<= 1) {
        int v = (t >= off) ? s[t - off] : 0;
        __syncthreads();
        s[t] += v;
        __syncthreads();
    }
    if (t < NB) {
        int b = (t == 0) ? 0 : s[t - 1];
        bucketBase[t] = b;
        bucketCursor[t] = b;
    }
    if (t == NB - 1) bucketBase[NB] = s[t];   // = E
}

// ---------- K3: partition edges into bucket runs (bulk reservation) ----------
__global__ void part_kernel(const int* __restrict__ row, const int* __restrict__ col,
                            int* __restrict__ bucketCursor, int2* __restrict__ pairs, int E) {
    __shared__ int h[NB];      // chunk histogram, then local cursor
    __shared__ int rbase[NB];  // reserved global run base
    int t = threadIdx.x;
    for (int i = t; i < NB; i += blockDim.x) h[i] = 0;
    __syncthreads();
    int base = blockIdx.x * CHUNK;
    int end = min(base + CHUNK, E);
    for (int e = base + t; e < end; e += blockDim.x)
        atomicAdd(&h[row[e] >> 8], 1);
    __syncthreads();
    for (int i = t; i < NB; i += blockDim.x) {
        int c = h[i];
        rbase[i] = c ? atomicAdd(&bucketCursor[i], c) : 0;
        h[i] = 0;  // reuse as local cursor
    }
    __syncthreads();
    for (int e = base + t; e < end; e += blockDim.x) {
        int r = row[e], c = col[e];
        int b = r >> 8;
        int pos = rbase[b] + atomicAdd(&h[b], 1);
        pairs[pos] = make_int2(r, c);
    }
}

// ---------- K4: per-bucket degree count -> dis ----------
__global__ void degdis_kernel(const int2* __restrict__ pairs, const int* __restrict__ bucketBase,
                              float* __restrict__ dis, int N) {
    __shared__ int cnt[RPB];
    int b = blockIdx.x, t = threadIdx.x;
    cnt[t] = 0;  // blockDim == RPB
    __syncthreads();
    int s = bucketBase[b], e = bucketBase[b + 1];
    for (int i = s + t; i < e; i += blockDim.x)
        atomicAdd(&cnt[pairs[i].x & (RPB - 1)], 1);
    __syncthreads();
    int rowid = b * RPB + t;
    if (rowid < N) dis[rowid] = (cnt[t] > 0) ? rsqrtf((float)cnt[t]) : 0.0f;
}

// ---------- K5: SpMM with LDS accumulator, one block per bucket ----------
__global__ void __launch_bounds__(1024)
spmm_lds_kernel(const float* __restrict__ x, const int2* __restrict__ pairs,
                const int* __restrict__ bucketBase, const float* __restrict__ dis,
                float* __restrict__ out, int N) {
    __shared__ float acc[RPB * D_FEAT];  // 64 KB
    int b = blockIdx.x;
    int t = threadIdx.x;
    int lane = t & 63;
    int wv = t >> 6;            // 0..15
    const int NW = 1024 / 64;   // 16 waves
    for (int i = t; i < RPB * D_FEAT; i += 1024) acc[i] = 0.0f;
    __syncthreads();
    int s = bucketBase[b], e = bucketBase[b + 1];
    for (int i = s + wv; i < e; i += NW) {
        int2 p = pairs[i];
        float dc = dis[p.y];
        float xv = x[(long long)p.y * D_FEAT + lane];
        atomicAdd(&acc[(p.x & (RPB - 1)) * D_FEAT + lane], dc * xv);
    }
    __syncthreads();
    int rowBase = b * RPB;
    for (int lr = wv; lr < RPB; lr += NW) {
        int r = rowBase + lr;
        if (r < N) out[(long long)r * D_FEAT + lane] = dis[r] * acc[lr * D_FEAT + lane];
    }
}

// ---------- fallback tier 1: round-3 CSR path ----------
#define SCAN_BLOCKS 256
#define SCAN_TPB 256

__global__ void deg_kernel(const int* __restrict__ row, int* __restrict__ deg, int E) {
    int i = blockIdx.x * blockDim.x + threadIdx.x;
    int stride = gridDim.x * blockDim.x;
    for (; i < E; i += stride) atomicAdd(&deg[row[i]], 1);
}
__global__ void dis_kernel(const int* __restrict__ deg, float* __restrict__ dis, int N) {
    int i = blockIdx.x * blockDim.x + threadIdx.x;
    if (i < N) { int d = deg[i]; dis[i] = (d > 0) ? rsqrtf((float)d) : 0.0f; }
}
__global__ void scan1_kernel(const int* __restrict__ deg, int* __restrict__ blockSums, int N) {
    __shared__ int sums[SCAN_TPB];
    int b = blockIdx.x, t = threadIdx.x;
    int CB = (N + SCAN_BLOCKS - 1) / SCAN_BLOCKS;
    int TB = (CB + SCAN_TPB - 1) / SCAN_TPB;
    int lo = b * CB + t * TB;
    int hi = min(lo + TB, min((b + 1) * CB, N));
    int s = 0;
    for (int i = lo; i < hi; ++i) s += deg[i];
    sums[t] = s;
    __syncthreads();
    for (int off = SCAN_TPB / 2; off > 0; off >>= 1) {
        if (t < off) sums[t] += sums[t + off];
        __syncthreads();
    }
    if (t == 0) blockSums[b] = sums[0];
}
__global__ void scan2_kernel(int* __restrict__ blockSums, int* __restrict__ blockOffs) {
    __shared__ int sums[SCAN_BLOCKS];
    int t = threadIdx.x;
    sums[t] = blockSums[t];
    __syncthreads();
    for (int off = 1; off < SCAN_BLOCKS; off <<= 1) {
        int v = (t >= off) ? sums[t - off] : 0;
        __syncthreads();
        sums[t] += v;
        __syncthreads();
    }
    blockOffs[t] = (t == 0) ? 0 : sums[t - 1];
}
__global__ void scan3_kernel(const int* __restrict__ deg, const int* __restrict__ blockOffs,
                             int* __restrict__ rowStart, int* __restrict__ cursor, int N, int E) {
    __shared__ int sums[SCAN_TPB];
    int b = blockIdx.x, t = threadIdx.x;
    int CB = (N + SCAN_BLOCKS - 1) / SCAN_BLOCKS;
    int TB = (CB + SCAN_TPB - 1) / SCAN_TPB;
    int lo = b * CB + t * TB;
    int hi = min(lo + TB, min((b + 1) * CB, N));
    int s = 0;
    for (int i = lo; i < hi; ++i) s += deg[i];
    sums[t] = s;
    __syncthreads();
    for (int off = 1; off < SCAN_TPB; off <<= 1) {
        int v = (t >= off) ? sums[t - off] : 0;
        __syncthreads();
        sums[t] += v;
        __syncthreads();
    }
    int base = blockOffs[b] + ((t == 0) ? 0 : sums[t - 1]);
    for (int i = lo; i < hi; ++i) {
        rowStart[i] = base;
        cursor[i] = base;
        base += deg[i];
    }
    if (b == 0 && t == 0) rowStart[N] = E;
}
__global__ void fill_kernel(const int* __restrict__ row, const int* __restrict__ col,
                            int* __restrict__ cursor, int* __restrict__ csr_col, int E) {
    int i = blockIdx.x * blockDim.x + threadIdx.x;
    int stride = gridDim.x * blockDim.x;
    for (; i < E; i += stride) {
        int pos = atomicAdd(&cursor[row[i]], 1);
        csr_col[pos] = col[i];
    }
}
__global__ void spmm_kernel(const float* __restrict__ x, const int* __restrict__ rowStart,
                            const int* __restrict__ csr_col, const float* __restrict__ dis,
                            float* __restrict__ out, int N) {
    int wid = (int)((blockIdx.x * (long long)blockDim.x + threadIdx.x) >> 6);
    int lane = threadIdx.x & 63;
    if (wid >= N) return;
    int s = rowStart[wid];
    int e = rowStart[wid + 1];
    float acc = 0.0f;
    for (int j = s; j < e; ++j) {
        int c = csr_col[j];
        acc += dis[c] * x[(long long)c * D_FEAT + lane];
    }
    out[(long long)wid * D_FEAT + lane] = dis[wid] * acc;
}

// ---------- fallback tier 2: atomic scatter ----------
__global__ void fb_deg_kernel(const int* __restrict__ row, float* __restrict__ deg, int E) {
    int i = blockIdx.x * blockDim.x + threadIdx.x;
    int stride = gridDim.x * blockDim.x;
    for (; i < E; i += stride) atomicAdd(&deg[row[i]], 1.0f);
}
__global__ void fb_dis_kernel(float* __restrict__ deg, int N) {
    int i = blockIdx.x * blockDim.x + threadIdx.x;
    if (i < N) { float d = deg[i]; deg[i] = (d > 0.0f) ? rsqrtf(d) : 0.0f; }
}
__global__ void fb_scatter_kernel(const float* __restrict__ x, const int* __restrict__ row,
                                  const int* __restrict__ col, const float* __restrict__ dis,
                                  float* __restrict__ out, long long total) {
    long long i = (long long)blockIdx.x * blockDim.x + threadIdx.x;
    long long stride = (long long)gridDim.x * blockDim.x;
    for (; i < total; i += stride) {
        int e = (int)(i >> 6);
        int d = (int)(i & 63);
        int r = row[e];
        int c = col[e];
        atomicAdd(&out[(long long)r * D_FEAT + d], dis[r] * dis[c] * x[(long long)c * D_FEAT + d]);
    }
}

extern "C" void kernel_launch(void* const* d_in, const int* in_sizes, int n_in,
                              void* d_out, int out_size, void* d_ws, size_t ws_size,
                              hipStream_t stream) {
    const float* x  = (const float*)d_in[0];
    const int*   ei = (const int*)d_in[1];
    int E = in_sizes[1] / 2;
    const int* row = ei;
    const int* col = ei + E;
    float* out = (float*)d_out;
    const int N = N_NODES;

    size_t need_main = (size_t)E * 8 + (size_t)(3 * NB + 1) * 4 + (size_t)N * 4;
    if (ws_size >= need_main) {
        char* ws = (char*)d_ws;
        int2*  pairs        = (int2*)ws;  ws += (size_t)E * 8;       // 8B-aligned first
        int*   bucketCnt    = (int*)ws;   ws += (size_t)NB * 4;
        int*   bucketBase   = (int*)ws;   ws += (size_t)(NB + 1) * 4;
        int*   bucketCursor = (int*)ws;   ws += (size_t)NB * 4;
        float* dis          = (float*)ws;

        hipMemsetAsync(bucketCnt, 0, (size_t)NB * sizeof(int), stream);
        int nChunks = (E + CHUNK - 1) / CHUNK;
        count_kernel<<<nChunks, 256, 0, stream>>>(row, bucketCnt, E);
        bscan_kernel<<<1, SCAN_T, 0, stream>>>(bucketCnt, bucketBase, bucketCursor);
        part_kernel<<<nChunks, 256, 0, stream>>>(row, col, bucketCursor, pairs, E);
        degdis_kernel<<<NB, RPB, 0, stream>>>(pairs, bucketBase, dis, N);
        spmm_lds_kernel<<<NB, 1024, 0, stream>>>(x, pairs, bucketBase, dis, out, N);
        return;
    }

    size_t need_csr = ((size_t)(3 * N + 1 + N + E) + 2 * SCAN_BLOCKS) * 4;
    if (ws_size >= need_csr) {
        char* ws = (char*)d_ws;
        int*   deg       = (int*)ws;    ws += (size_t)N * 4;
        int*   rowStart  = (int*)ws;    ws += (size_t)(N + 1) * 4;
        int*   cursor    = (int*)ws;    ws += (size_t)N * 4;
        float* dis       = (float*)ws;  ws += (size_t)N * 4;
        int*   blockSums = (int*)ws;    ws += (size_t)SCAN_BLOCKS * 4;
        int*   blockOffs = (int*)ws;    ws += (size_t)SCAN_BLOCKS * 4;
        int*   csr_col   = (int*)ws;

        hipMemsetAsync(deg, 0, (size_t)N * sizeof(int), stream);
        deg_kernel<<<2048, 256, 0, stream>>>(row, deg, E);
        dis_kernel<<<(N + 255) / 256, 256, 0, stream>>>(deg, dis, N);
        scan1_kernel<<<SCAN_BLOCKS, SCAN_TPB, 0, stream>>>(deg, blockSums, N);
        scan2_kernel<<<1, SCAN_BLOCKS, 0, stream>>>(blockSums, blockOffs);
        scan3_kernel<<<SCAN_BLOCKS, SCAN_TPB, 0, stream>>>(deg, blockOffs, rowStart, cursor, N, E);
        fill_kernel<<<2048, 256, 0, stream>>>(row, col, cursor, csr_col, E);
        spmm_kernel<<<(N + 3) / 4, 256, 0, stream>>>(x, rowStart, csr_col, dis, out, N);
        return;
    }

    // tier 2
    float* deg = (float*)d_ws;
    hipMemsetAsync(out, 0, (size_t)out_size * sizeof(float), stream);
    hipMemsetAsync(deg, 0, (size_t)N * sizeof(float), stream);
    fb_deg_kernel<<<2048, 256, 0, stream>>>(row, deg, E);
    fb_dis_kernel<<<(N + 255) / 256, 256, 0, stream>>>(deg, N);
    fb_scatter_kernel<<<4096, 256, 0, stream>>>(x, row, col, deg, out, (long long)E * D_FEAT);
}

// Round 5
// 139.804 us; speedup vs baseline: 5.3385x; 5.3385x over previous
//
#include <hip/hip_runtime.h>

#define N_NODES 100000
#define D_FEAT 64
#define RPB 256                               // rows per bucket
#define NB ((N_NODES + RPB - 1) / RPB)        // 391 buckets
#define CHUNK 4096                            // edges per partition block
#define SCAN_T 512
#define COL_BITS 17                           // N_NODES < 2^17
#define COL_MASK ((1 << COL_BITS) - 1)

// ---------- K1: bucket-size histogram ----------
__global__ void count_kernel(const int* __restrict__ row, int* __restrict__ bucketCnt, int E) {
    __shared__ int h[NB];
    for (int i = threadIdx.x; i < NB; i += blockDim.x) h[i] = 0;
    __syncthreads();
    int base = blockIdx.x * CHUNK;
    int end = min(base + CHUNK, E);
    for (int e = base + threadIdx.x; e < end; e += blockDim.x)
        atomicAdd(&h[row[e] >> 8], 1);
    __syncthreads();
    for (int i = threadIdx.x; i < NB; i += blockDim.x)
        if (h[i]) atomicAdd(&bucketCnt[i], h[i]);
}

// ---------- K2: scan bucket sizes -> base & cursor ----------
__global__ void bscan_kernel(const int* __restrict__ bucketCnt, int* __restrict__ bucketBase,
                             int* __restrict__ bucketCursor) {
    __shared__ int s[SCAN_T];
    int t = threadIdx.x;
    s[t] = (t < NB) ? bucketCnt[t] : 0;
    __syncthreads();
    for (int off = 1; off < SCAN_T; off <<= 1) {
        int v = (t >= off) ? s[t - off] : 0;
        __syncthreads();
        s[t] += v;
        __syncthreads();
    }
    if (t < NB) {
        int b = (t == 0) ? 0 : s[t - 1];
        bucketBase[t] = b;
        bucketCursor[t] = b;
    }
    if (t == NB - 1) bucketBase[NB] = s[t];   // = E
}

// ---------- K3: partition edges into bucket runs (bulk reservation, packed) ----------
__global__ void part_kernel(const int* __restrict__ row, const int* __restrict__ col,
                            int* __restrict__ bucketCursor, int* __restrict__ packed, int E) {
    __shared__ int h[NB];      // chunk histogram, then local cursor
    __shared__ int rbase[NB];  // reserved global run base
    int t = threadIdx.x;
    for (int i = t; i < NB; i += blockDim.x) h[i] = 0;
    __syncthreads();
    int base = blockIdx.x * CHUNK;
    int end = min(base + CHUNK, E);
    for (int e = base + t; e < end; e += blockDim.x)
        atomicAdd(&h[row[e] >> 8], 1);
    __syncthreads();
    for (int i = t; i < NB; i += blockDim.x) {
        int c = h[i];
        rbase[i] = c ? atomicAdd(&bucketCursor[i], c) : 0;
        h[i] = 0;  // reuse as local cursor
    }
    __syncthreads();
    for (int e = base + t; e < end; e += blockDim.x) {
        int r = row[e], c = col[e];
        int b = r >> 8;
        int pos = rbase[b] + atomicAdd(&h[b], 1);
        packed[pos] = ((r & (RPB - 1)) << COL_BITS) | c;
    }
}

// ---------- K4: per-bucket counting sort -> CSR + rowStart + dis ----------
__global__ void __launch_bounds__(256)
csr_build_kernel(const int* __restrict__ packed, const int* __restrict__ bucketBase,
                 int* __restrict__ rowStart, int* __restrict__ csr_col,
                 float* __restrict__ dis, int N, int E) {
    __shared__ int cnt[RPB];
    __shared__ int off[RPB];
    __shared__ int cur[RPB];
    int b = blockIdx.x, t = threadIdx.x;
    cnt[t] = 0;
    __syncthreads();
    int s = bucketBase[b], e = bucketBase[b + 1];
    for (int i = s + t; i < e; i += 256)
        atomicAdd(&cnt[packed[i] >> COL_BITS], 1);
    __syncthreads();
    int v = cnt[t];
    off[t] = v;
    __syncthreads();
    for (int o = 1; o < RPB; o <<= 1) {   // inclusive scan
        int u = (t >= o) ? off[t - o] : 0;
        __syncthreads();
        off[t] += u;
        __syncthreads();
    }
    int ex = off[t] - v;                  // exclusive offset
    cur[t] = ex;
    int r = b * RPB + t;
    if (r < N) {
        rowStart[r] = s + ex;
        dis[r] = (v > 0) ? rsqrtf((float)v) : 0.0f;
    }
    if (b == NB - 1 && t == 0) rowStart[N] = E;
    __syncthreads();
    for (int i = s + t; i < e; i += 256) {
        int p = packed[i];
        int lr = p >> COL_BITS;
        int pos = s + atomicAdd(&cur[lr], 1);
        csr_col[pos] = p & COL_MASK;
    }
}

// ---------- K5: SpMM, one wave per row, lane = feature ----------
__global__ void spmm_kernel(const float* __restrict__ x,
                            const int* __restrict__ rowStart,
                            const int* __restrict__ csr_col,
                            const float* __restrict__ dis,
                            float* __restrict__ out, int N) {
    int wid = (int)((blockIdx.x * (long long)blockDim.x + threadIdx.x) >> 6);
    int lane = threadIdx.x & 63;
    if (wid >= N) return;
    int s = rowStart[wid];
    int e = rowStart[wid + 1];
    float acc = 0.0f;
    int j = s;
    for (; j + 3 < e; j += 4) {
        int c0 = csr_col[j];
        int c1 = csr_col[j + 1];
        int c2 = csr_col[j + 2];
        int c3 = csr_col[j + 3];
        float d0 = dis[c0], d1 = dis[c1], d2 = dis[c2], d3 = dis[c3];
        float x0 = x[(long long)c0 * D_FEAT + lane];
        float x1 = x[(long long)c1 * D_FEAT + lane];
        float x2 = x[(long long)c2 * D_FEAT + lane];
        float x3 = x[(long long)c3 * D_FEAT + lane];
        acc += d0 * x0 + d1 * x1 + d2 * x2 + d3 * x3;
    }
    for (; j < e; ++j) {
        int c = csr_col[j];
        acc += dis[c] * x[(long long)c * D_FEAT + lane];
    }
    out[(long long)wid * D_FEAT + lane] = dis[wid] * acc;
}

// ---------- fallback tier 1: round-3 CSR path ----------
#define SCAN_BLOCKS 256
#define SCAN_TPB 256

__global__ void deg_kernel(const int* __restrict__ row, int* __restrict__ deg, int E) {
    int i = blockIdx.x * blockDim.x + threadIdx.x;
    int stride = gridDim.x * blockDim.x;
    for (; i < E; i += stride) atomicAdd(&deg[row[i]], 1);
}
__global__ void dis_kernel(const int* __restrict__ deg, float* __restrict__ dis, int N) {
    int i = blockIdx.x * blockDim.x + threadIdx.x;
    if (i < N) { int d = deg[i]; dis[i] = (d > 0) ? rsqrtf((float)d) : 0.0f; }
}
__global__ void scan1_kernel(const int* __restrict__ deg, int* __restrict__ blockSums, int N) {
    __shared__ int sums[SCAN_TPB];
    int b = blockIdx.x, t = threadIdx.x;
    int CB = (N + SCAN_BLOCKS - 1) / SCAN_BLOCKS;
    int TB = (CB + SCAN_TPB - 1) / SCAN_TPB;
    int lo = b * CB + t * TB;
    int hi = min(lo + TB, min((b + 1) * CB, N));
    int s = 0;
    for (int i = lo; i < hi; ++i) s += deg[i];
    sums[t] = s;
    __syncthreads();
    for (int off = SCAN_TPB / 2; off > 0; off >>= 1) {
        if (t < off) sums[t] += sums[t + off];
        __syncthreads();
    }
    if (t == 0) blockSums[b] = sums[0];
}
__global__ void scan2_kernel(int* __restrict__ blockSums, int* __restrict__ blockOffs) {
    __shared__ int sums[SCAN_BLOCKS];
    int t = threadIdx.x;
    sums[t] = blockSums[t];
    __syncthreads();
    for (int off = 1; off < SCAN_BLOCKS; off <<= 1) {
        int v = (t >= off) ? sums[t - off] : 0;
        __syncthreads();
        sums[t] += v;
        __syncthreads();
    }
    blockOffs[t] = (t == 0) ? 0 : sums[t - 1];
}
__global__ void scan3_kernel(const int* __restrict__ deg, const int* __restrict__ blockOffs,
                             int* __restrict__ rowStart, int* __restrict__ cursor, int N, int E) {
    __shared__ int sums[SCAN_TPB];
    int b = blockIdx.x, t = threadIdx.x;
    int CB = (N + SCAN_BLOCKS - 1) / SCAN_BLOCKS;
    int TB = (CB + SCAN_TPB - 1) / SCAN_TPB;
    int lo = b * CB + t * TB;
    int hi = min(lo + TB, min((b + 1) * CB, N));
    int s = 0;
    for (int i = lo; i < hi; ++i) s += deg[i];
    sums[t] = s;
    __syncthreads();
    for (int off = 1; off < SCAN_TPB; off <<= 1) {
        int v = (t >= off) ? sums[t - off] : 0;
        __syncthreads();
        sums[t] += v;
        __syncthreads();
    }
    int base = blockOffs[b] + ((t == 0) ? 0 : sums[t - 1]);
    for (int i = lo; i < hi; ++i) {
        rowStart[i] = base;
        cursor[i] = base;
        base += deg[i];
    }
    if (b == 0 && t == 0) rowStart[N] = E;
}
__global__ void fill_kernel(const int* __restrict__ row, const int* __restrict__ col,
                            int* __restrict__ cursor, int* __restrict__ csr_col, int E) {
    int i = blockIdx.x * blockDim.x + threadIdx.x;
    int stride = gridDim.x * blockDim.x;
    for (; i < E; i += stride) {
        int pos = atomicAdd(&cursor[row[i]], 1);
        csr_col[pos] = col[i];
    }
}

// ---------- fallback tier 2: atomic scatter ----------
__global__ void fb_deg_kernel(const int* __restrict__ row, float* __restrict__ deg, int E) {
    int i = blockIdx.x * blockDim.x + threadIdx.x;
    int stride = gridDim.x * blockDim.x;
    for (; i < E; i += stride) atomicAdd(&deg[row[i]], 1.0f);
}
__global__ void fb_dis_kernel(float* __restrict__ deg, int N) {
    int i = blockIdx.x * blockDim.x + threadIdx.x;
    if (i < N) { float d = deg[i]; deg[i] = (d > 0.0f) ? rsqrtf(d) : 0.0f; }
}
__global__ void fb_scatter_kernel(const float* __restrict__ x, const int* __restrict__ row,
                                  const int* __restrict__ col, const float* __restrict__ dis,
                                  float* __restrict__ out, long long total) {
    long long i = (long long)blockIdx.x * blockDim.x + threadIdx.x;
    long long stride = (long long)gridDim.x * blockDim.x;
    for (; i < total; i += stride) {
        int e = (int)(i >> 6);
        int d = (int)(i & 63);
        int r = row[e];
        int c = col[e];
        atomicAdd(&out[(long long)r * D_FEAT + d], dis[r] * dis[c] * x[(long long)c * D_FEAT + d]);
    }
}

extern "C" void kernel_launch(void* const* d_in, const int* in_sizes, int n_in,
                              void* d_out, int out_size, void* d_ws, size_t ws_size,
                              hipStream_t stream) {
    const float* x  = (const float*)d_in[0];
    const int*   ei = (const int*)d_in[1];
    int E = in_sizes[1] / 2;
    const int* row = ei;
    const int* col = ei + E;
    float* out = (float*)d_out;
    const int N = N_NODES;

    size_t need_main = (size_t)E * 4 * 2                // packed + csr_col
                     + (size_t)(N + 1) * 4 + (size_t)N * 4   // rowStart + dis
                     + (size_t)(3 * NB + 1) * 4;        // bucketCnt/Base/Cursor
    if (ws_size >= need_main) {
        char* ws = (char*)d_ws;
        int*   packed       = (int*)ws;   ws += (size_t)E * 4;
        int*   csr_col      = (int*)ws;   ws += (size_t)E * 4;
        int*   rowStart     = (int*)ws;   ws += (size_t)(N + 1) * 4;
        float* dis          = (float*)ws; ws += (size_t)N * 4;
        int*   bucketCnt    = (int*)ws;   ws += (size_t)NB * 4;
        int*   bucketBase   = (int*)ws;   ws += (size_t)(NB + 1) * 4;
        int*   bucketCursor = (int*)ws;

        hipMemsetAsync(bucketCnt, 0, (size_t)NB * sizeof(int), stream);
        int nChunks = (E + CHUNK - 1) / CHUNK;
        count_kernel<<<nChunks, 256, 0, stream>>>(row, bucketCnt, E);
        bscan_kernel<<<1, SCAN_T, 0, stream>>>(bucketCnt, bucketBase, bucketCursor);
        part_kernel<<<nChunks, 256, 0, stream>>>(row, col, bucketCursor, packed, E);
        csr_build_kernel<<<NB, RPB, 0, stream>>>(packed, bucketBase, rowStart, csr_col, dis, N, E);
        spmm_kernel<<<(N + 3) / 4, 256, 0, stream>>>(x, rowStart, csr_col, dis, out, N);
        return;
    }

    size_t need_csr = ((size_t)(3 * N + 1 + N + E) + 2 * SCAN_BLOCKS) * 4;
    if (ws_size >= need_csr) {
        char* ws = (char*)d_ws;
        int*   deg       = (int*)ws;    ws += (size_t)N * 4;
        int*   rowStart  = (int*)ws;    ws += (size_t)(N + 1) * 4;
        int*   cursor    = (int*)ws;    ws += (size_t)N * 4;
        float* dis       = (float*)ws;  ws += (size_t)N * 4;
        int*   blockSums = (int*)ws;    ws += (size_t)SCAN_BLOCKS * 4;
        int*   blockOffs = (int*)ws;    ws += (size_t)SCAN_BLOCKS * 4;
        int*   csr_col   = (int*)ws;

        hipMemsetAsync(deg, 0, (size_t)N * sizeof(int), stream);
        deg_kernel<<<2048, 256, 0, stream>>>(row, deg, E);
        dis_kernel<<<(N + 255) / 256, 256, 0, stream>>>(deg, dis, N);
        scan1_kernel<<<SCAN_BLOCKS, SCAN_TPB, 0, stream>>>(deg, blockSums, N);
        scan2_kernel<<<1, SCAN_BLOCKS, 0, stream>>>(blockSums, blockOffs);
        scan3_kernel<<<SCAN_BLOCKS, SCAN_TPB, 0, stream>>>(deg, blockOffs, rowStart, cursor, N, E);
        fill_kernel<<<2048, 256, 0, stream>>>(row, col, cursor, csr_col, E);
        spmm_kernel<<<(N + 3) / 4, 256, 0, stream>>>(x, rowStart, csr_col, dis, out, N);
        return;
    }

    // tier 2
    float* deg = (float*)d_ws;
    hipMemsetAsync(out, 0, (size_t)out_size * sizeof(float), stream);
    hipMemsetAsync(deg, 0, (size_t)N * sizeof(float), stream);
    fb_deg_kernel<<<2048, 256, 0, stream>>>(row, deg, E);
    fb_dis_kernel<<<(N + 255) / 256, 256, 0, stream>>>(deg, N);
    fb_scatter_kernel<<<4096, 256, 0, stream>>>(x, row, col, deg, out, (long long)E * D_FEAT);
}

// Round 6
// 121.314 us; speedup vs baseline: 6.1522x; 1.1524x over previous
//
#include <hip/hip_runtime.h>
#include <hip/hip_fp16.h>

#define N_NODES 100000
#define D_FEAT 64
#define RPB 256                               // rows per bucket
#define NB ((N_NODES + RPB - 1) / RPB)        // 391 buckets
#define CHUNK 4096                            // edges per partition block
#define SCAN_T 512
#define COL_BITS 17                           // N_NODES < 2^17
#define COL_MASK ((1 << COL_BITS) - 1)

// ---------- K1: bucket-size histogram ----------
__global__ void count_kernel(const int* __restrict__ row, int* __restrict__ bucketCnt, int E) {
    __shared__ int h[NB];
    for (int i = threadIdx.x; i < NB; i += blockDim.x) h[i] = 0;
    __syncthreads();
    int base = blockIdx.x * CHUNK;
    int end = min(base + CHUNK, E);
    for (int e = base + threadIdx.x; e < end; e += blockDim.x)
        atomicAdd(&h[row[e] >> 8], 1);
    __syncthreads();
    for (int i = threadIdx.x; i < NB; i += blockDim.x)
        if (h[i]) atomicAdd(&bucketCnt[i], h[i]);
}

// ---------- K2: scan bucket sizes -> base & cursor ----------
__global__ void bscan_kernel(const int* __restrict__ bucketCnt, int* __restrict__ bucketBase,
                             int* __restrict__ bucketCursor) {
    __shared__ int s[SCAN_T];
    int t = threadIdx.x;
    s[t] = (t < NB) ? bucketCnt[t] : 0;
    __syncthreads();
    for (int off = 1; off < SCAN_T; off <<= 1) {
        int v = (t >= off) ? s[t - off] : 0;
        __syncthreads();
        s[t] += v;
        __syncthreads();
    }
    if (t < NB) {
        int b = (t == 0) ? 0 : s[t - 1];
        bucketBase[t] = b;
        bucketCursor[t] = b;
    }
    if (t == NB - 1) bucketBase[NB] = s[t];   // = E
}

// ---------- K3: partition edges into bucket runs (bulk reservation, packed) ----------
__global__ void part_kernel(const int* __restrict__ row, const int* __restrict__ col,
                            int* __restrict__ bucketCursor, int* __restrict__ packed, int E) {
    __shared__ int h[NB];      // chunk histogram, then local cursor
    __shared__ int rbase[NB];  // reserved global run base
    int t = threadIdx.x;
    for (int i = t; i < NB; i += blockDim.x) h[i] = 0;
    __syncthreads();
    int base = blockIdx.x * CHUNK;
    int end = min(base + CHUNK, E);
    for (int e = base + t; e < end; e += blockDim.x)
        atomicAdd(&h[row[e] >> 8], 1);
    __syncthreads();
    for (int i = t; i < NB; i += blockDim.x) {
        int c = h[i];
        rbase[i] = c ? atomicAdd(&bucketCursor[i], c) : 0;
        h[i] = 0;  // reuse as local cursor
    }
    __syncthreads();
    for (int e = base + t; e < end; e += blockDim.x) {
        int r = row[e], c = col[e];
        int b = r >> 8;
        int pos = rbase[b] + atomicAdd(&h[b], 1);
        packed[pos] = ((r & (RPB - 1)) << COL_BITS) | c;
    }
}

// ---------- K4: per-bucket counting sort -> CSR + rowStart + dis ----------
__global__ void __launch_bounds__(256)
csr_build_kernel(const int* __restrict__ packed, const int* __restrict__ bucketBase,
                 int* __restrict__ rowStart, int* __restrict__ csr_col,
                 float* __restrict__ dis, int N, int E) {
    __shared__ int cnt[RPB];
    __shared__ int off[RPB];
    __shared__ int cur[RPB];
    int b = blockIdx.x, t = threadIdx.x;
    cnt[t] = 0;
    __syncthreads();
    int s = bucketBase[b], e = bucketBase[b + 1];
    for (int i = s + t; i < e; i += 256)
        atomicAdd(&cnt[packed[i] >> COL_BITS], 1);
    __syncthreads();
    int v = cnt[t];
    off[t] = v;
    __syncthreads();
    for (int o = 1; o < RPB; o <<= 1) {   // inclusive scan
        int u = (t >= o) ? off[t - o] : 0;
        __syncthreads();
        off[t] += u;
        __syncthreads();
    }
    int ex = off[t] - v;                  // exclusive offset
    cur[t] = ex;
    int r = b * RPB + t;
    if (r < N) {
        rowStart[r] = s + ex;
        dis[r] = (v > 0) ? rsqrtf((float)v) : 0.0f;
    }
    if (b == NB - 1 && t == 0) rowStart[N] = E;
    __syncthreads();
    for (int i = s + t; i < e; i += 256) {
        int p = packed[i];
        int lr = p >> COL_BITS;
        int pos = s + atomicAdd(&cur[lr], 1);
        csr_col[pos] = p & COL_MASK;
    }
}

// ---------- K5: prescale + fp16 convert: xs[c][f] = fp16(dis[c]*x[c][f]) ----------
__global__ void convert_kernel(const float* __restrict__ x, const float* __restrict__ dis,
                               __half* __restrict__ xs, int total4) {
    int i = blockIdx.x * blockDim.x + threadIdx.x;   // one thread per 4 features
    if (i >= total4) return;
    int node = i >> 4;
    float d = dis[node];
    float4 v = *(const float4*)(x + ((long long)i << 2));
    __half2 a = __floats2half2_rn(d * v.x, d * v.y);
    __half2 b = __floats2half2_rn(d * v.z, d * v.w);
    __half2* p = (__half2*)(xs + ((long long)i << 2));
    p[0] = a;
    p[1] = b;
}

// ---------- K6: SpMM fp16 gather: wave = row, 4 edge-groups x 16 feature-quads ----------
__device__ __forceinline__ void acc_add(float4& acc, uint2 v) {
    float2 f0 = __half22float2(*(__half2*)&v.x);
    float2 f1 = __half22float2(*(__half2*)&v.y);
    acc.x += f0.x; acc.y += f0.y; acc.z += f1.x; acc.w += f1.y;
}

__global__ void __launch_bounds__(256)
spmm_h4_kernel(const __half* __restrict__ xs,
               const int* __restrict__ rowStart,
               const int* __restrict__ csr_col,
               const float* __restrict__ dis,
               float* __restrict__ out, int N) {
    int wid = (int)((blockIdx.x * (long long)blockDim.x + threadIdx.x) >> 6);
    if (wid >= N) return;
    int lane = threadIdx.x & 63;
    int g = lane >> 4;          // edge slot 0..3
    int q = lane & 15;          // feature quad: features 4q..4q+3
    int s = rowStart[wid], e = rowStart[wid + 1];
    float4 acc = make_float4(0.f, 0.f, 0.f, 0.f);
    int j = s;
    for (; j + 8 <= e; j += 8) {
        int c0 = csr_col[j + g];
        int c1 = csr_col[j + 4 + g];
        uint2 v0 = *(const uint2*)(xs + (((long long)c0) << 6) + (q << 2));
        uint2 v1 = *(const uint2*)(xs + (((long long)c1) << 6) + (q << 2));
        acc_add(acc, v0);
        acc_add(acc, v1);
    }
    if (j + 4 <= e) {
        int c = csr_col[j + g];
        uint2 v = *(const uint2*)(xs + (((long long)c) << 6) + (q << 2));
        acc_add(acc, v);
        j += 4;
    }
    int rem = e - j;            // 0..3
    if (g < rem) {
        int c = csr_col[j + g];
        uint2 v = *(const uint2*)(xs + (((long long)c) << 6) + (q << 2));
        acc_add(acc, v);
    }
    // reduce across the 4 edge groups (lanes differing in bits 4,5)
    acc.x += __shfl_xor(acc.x, 16);
    acc.y += __shfl_xor(acc.y, 16);
    acc.z += __shfl_xor(acc.z, 16);
    acc.w += __shfl_xor(acc.w, 16);
    acc.x += __shfl_xor(acc.x, 32);
    acc.y += __shfl_xor(acc.y, 32);
    acc.z += __shfl_xor(acc.z, 32);
    acc.w += __shfl_xor(acc.w, 32);
    if (g == 0) {
        float dr = dis[wid];
        float4 o = make_float4(dr * acc.x, dr * acc.y, dr * acc.z, dr * acc.w);
        *(float4*)(out + ((long long)wid << 6) + (q << 2)) = o;
    }
}

// ---------- fallback: fp32 SpMM (round-5 path) ----------
__global__ void spmm_kernel(const float* __restrict__ x,
                            const int* __restrict__ rowStart,
                            const int* __restrict__ csr_col,
                            const float* __restrict__ dis,
                            float* __restrict__ out, int N) {
    int wid = (int)((blockIdx.x * (long long)blockDim.x + threadIdx.x) >> 6);
    int lane = threadIdx.x & 63;
    if (wid >= N) return;
    int s = rowStart[wid];
    int e = rowStart[wid + 1];
    float acc = 0.0f;
    int j = s;
    for (; j + 3 < e; j += 4) {
        int c0 = csr_col[j];
        int c1 = csr_col[j + 1];
        int c2 = csr_col[j + 2];
        int c3 = csr_col[j + 3];
        float d0 = dis[c0], d1 = dis[c1], d2 = dis[c2], d3 = dis[c3];
        float x0 = x[(long long)c0 * D_FEAT + lane];
        float x1 = x[(long long)c1 * D_FEAT + lane];
        float x2 = x[(long long)c2 * D_FEAT + lane];
        float x3 = x[(long long)c3 * D_FEAT + lane];
        acc += d0 * x0 + d1 * x1 + d2 * x2 + d3 * x3;
    }
    for (; j < e; ++j) {
        int c = csr_col[j];
        acc += dis[c] * x[(long long)c * D_FEAT + lane];
    }
    out[(long long)wid * D_FEAT + lane] = dis[wid] * acc;
}

// ---------- fallback tier 2: atomic scatter ----------
__global__ void fb_deg_kernel(const int* __restrict__ row, float* __restrict__ deg, int E) {
    int i = blockIdx.x * blockDim.x + threadIdx.x;
    int stride = gridDim.x * blockDim.x;
    for (; i < E; i += stride) atomicAdd(&deg[row[i]], 1.0f);
}
__global__ void fb_dis_kernel(float* __restrict__ deg, int N) {
    int i = blockIdx.x * blockDim.x + threadIdx.x;
    if (i < N) { float d = deg[i]; deg[i] = (d > 0.0f) ? rsqrtf(d) : 0.0f; }
}
__global__ void fb_scatter_kernel(const float* __restrict__ x, const int* __restrict__ row,
                                  const int* __restrict__ col, const float* __restrict__ dis,
                                  float* __restrict__ out, long long total) {
    long long i = (long long)blockIdx.x * blockDim.x + threadIdx.x;
    long long stride = (long long)gridDim.x * blockDim.x;
    for (; i < total; i += stride) {
        int e = (int)(i >> 6);
        int d = (int)(i & 63);
        int r = row[e];
        int c = col[e];
        atomicAdd(&out[(long long)r * D_FEAT + d], dis[r] * dis[c] * x[(long long)c * D_FEAT + d]);
    }
}

extern "C" void kernel_launch(void* const* d_in, const int* in_sizes, int n_in,
                              void* d_out, int out_size, void* d_ws, size_t ws_size,
                              hipStream_t stream) {
    const float* x  = (const float*)d_in[0];
    const int*   ei = (const int*)d_in[1];
    int E = in_sizes[1] / 2;
    const int* row = ei;
    const int* col = ei + E;
    float* out = (float*)d_out;
    const int N = N_NODES;

    // layout A (fp16 path): packed[E] csr_col[E] xs[N*64 halves] rowStart[N+1] dis[N] buckets
    size_t need_h = (size_t)E * 4 * 2 + (size_t)N * D_FEAT * 2
                  + (size_t)(N + 1) * 4 + (size_t)N * 4 + (size_t)(3 * NB + 1) * 4;
    // layout B (fp32 path): same minus xs
    size_t need_f = (size_t)E * 4 * 2
                  + (size_t)(N + 1) * 4 + (size_t)N * 4 + (size_t)(3 * NB + 1) * 4;

    if (ws_size >= need_f) {
        bool use_h = (ws_size >= need_h);
        char* ws = (char*)d_ws;
        int*    packed       = (int*)ws;    ws += (size_t)E * 4;
        int*    csr_col      = (int*)ws;    ws += (size_t)E * 4;
        __half* xs           = (__half*)ws; if (use_h) ws += (size_t)N * D_FEAT * 2;
        int*    rowStart     = (int*)ws;    ws += (size_t)(N + 1) * 4;
        float*  dis          = (float*)ws;  ws += (size_t)N * 4;
        int*    bucketCnt    = (int*)ws;    ws += (size_t)NB * 4;
        int*    bucketBase   = (int*)ws;    ws += (size_t)(NB + 1) * 4;
        int*    bucketCursor = (int*)ws;

        hipMemsetAsync(bucketCnt, 0, (size_t)NB * sizeof(int), stream);
        int nChunks = (E + CHUNK - 1) / CHUNK;
        count_kernel<<<nChunks, 256, 0, stream>>>(row, bucketCnt, E);
        bscan_kernel<<<1, SCAN_T, 0, stream>>>(bucketCnt, bucketBase, bucketCursor);
        part_kernel<<<nChunks, 256, 0, stream>>>(row, col, bucketCursor, packed, E);
        csr_build_kernel<<<NB, RPB, 0, stream>>>(packed, bucketBase, rowStart, csr_col, dis, N, E);
        if (use_h) {
            int total4 = N * (D_FEAT / 4);
            convert_kernel<<<(total4 + 255) / 256, 256, 0, stream>>>(x, dis, xs, total4);
            spmm_h4_kernel<<<(N + 3) / 4, 256, 0, stream>>>(xs, rowStart, csr_col, dis, out, N);
        } else {
            spmm_kernel<<<(N + 3) / 4, 256, 0, stream>>>(x, rowStart, csr_col, dis, out, N);
        }
        return;
    }

    // tier 2: atomic scatter
    float* deg = (float*)d_ws;
    hipMemsetAsync(out, 0, (size_t)out_size * sizeof(float), stream);
    hipMemsetAsync(deg, 0, (size_t)N * sizeof(float), stream);
    fb_deg_kernel<<<2048, 256, 0, stream>>>(row, deg, E);
    fb_dis_kernel<<<(N + 255) / 256, 256, 0, stream>>>(deg, N);
    fb_scatter_kernel<<<4096, 256, 0, stream>>>(x, row, col, deg, out, (long long)E * D_FEAT);
}